// Round 6
// baseline (64.840 us; speedup 1.0000x reference)
//
#include <hip/hip_runtime.h>
#include <math.h>

#define NJ 128
#define HH 512
#define WW 512
#define FEPS 1e-7f
#define TS  16          // tile size (half-res cells) per block
#define THS (TS + 2)    // 18: tile + 1-cell halo
#define TLP 20          // padded LDS row pitch (floats/ints)

// ---------------------------------------------------------------- eig helper
// 2x2 symmetric eigendecomposition, ascending order (matches jnp.linalg.eigh).
// Bit-identical to the validated rounds 2-5.
__device__ __forceinline__ void eig2x2(float a, float b, float c,
                                       float& l0, float& l1,
                                       float& V00, float& V10, float& V01, float& V11) {
    float mean = 0.5f * (a + c);
    float diff = 0.5f * (a - c);
    float disc = sqrtf(diff * diff + b * b);
    l0 = mean - disc;   // smaller
    l1 = mean + disc;   // larger
    float ux, uy;
    if (diff >= 0.f) { ux = diff + disc; uy = b; }
    else             { ux = b;           uy = disc - diff; }
    float nn = sqrtf(ux * ux + uy * uy);
    if (nn > 0.f) { ux /= nn; uy /= nn; } else { ux = 1.f; uy = 0.f; }
    V00 = -uy; V10 = ux;   // column 0 (l0)
    V01 =  ux; V11 = uy;   // column 1 (l1)
}

// ---------------------------------------------------------------- init (blocks race otherwise)
__global__ void k_init(unsigned* __restrict__ g) {
    int t = threadIdx.x;
    if (t < 3 * NJ + 1) g[t] = 0u;   // gm[256], cnt[128], bar[1]
}

// ---------------------------------------------------------------- fused kernel
// Per block: (1) recompute all 128 Gaussian params into LDS; (2) compute the
// 18x18 (tile+halo) half-res val/vor into LDS (redundant across blocks - VALU
// is nearly idle, global round-trips are not); (3) quad-per-thread markers +
// bilinear entirely from LDS; (4) wave segmented prefix-max -> leader
// device-scope atomics; (5) last-finished block computes the loss.
__global__ __launch_bounds__(256) void k_fused(
        const float* __restrict__ mu, const float* __restrict__ sigma,
        const int* __restrict__ label, const float* __restrict__ pos_thres,
        const float* __restrict__ neg_thres,
        unsigned* __restrict__ gm, unsigned* __restrict__ cnt,
        unsigned* __restrict__ bar, float* __restrict__ out) {
    __shared__ float4 lp[NJ];          // mmx, mmy, ia, ib2
    __shared__ float  lic[NJ];         // ic
    __shared__ float4 lvv[NJ];         // V00, V10, V01, V11
    __shared__ float2 lmu[NJ];         // mux, muy
    __shared__ float  lpt[NJ], lnt[NJ];
    __shared__ float  lls0[NJ], lls1[NJ];
    __shared__ float  tval[THS][TLP];
    __shared__ int    tvor[THS][TLP];
    __shared__ float  lb[NJ], sv[NJ];
    __shared__ int    si[NJ];
    __shared__ int    isLast;

    int tid = threadIdx.x;
    // ---- per-block param setup (identical arithmetic in every block -> identical bits)
    if (tid < NJ) {
        int j = tid;
        float a = sigma[j * 4 + 0];
        float b = sigma[j * 4 + 1];
        float c = sigma[j * 4 + 3];
        float l0, l1, V00, V10, V01, V11;
        eig2x2(a, b, c, l0, l1, V00, V10, V01, V11);
        float gmean = sqrtf(l0 * l1);
        float lsc0 = l0 / gmean * 4096.f;
        float lsc1 = l1 / gmean * 4096.f;
        float s00 = (V00 * V00 * lsc0 + V01 * V01 * lsc1) * 0.25f;
        float s01 = (V00 * V10 * lsc0 + V01 * V11 * lsc1) * 0.25f;
        float s11 = (V10 * V10 * lsc0 + V11 * V11 * lsc1) * 0.25f;
        float det = s00 * s11 - s01 * s01;
        float4 q;
        q.x = rintf(mu[j * 2 + 0] * 0.5f);   // jnp.round = ties-to-even = rintf
        q.y = rintf(mu[j * 2 + 1] * 0.5f);
        q.z =  s11 / det;                    // ia
        q.w = -2.f * s01 / det;              // ib2
        lp[j]  = q;
        lic[j] = s00 / det;                  // ic
        lvv[j] = make_float4(V00, V10, V01, V11);
        lmu[j] = make_float2(mu[j * 2 + 0], mu[j * 2 + 1]);
        int cl = label[j];
        lpt[j] = pos_thres[cl];
        lnt[j] = neg_thres[cl];
        lls0[j] = l0; lls1[j] = l1;
    }
    __syncthreads();

    int A0 = (blockIdx.x >> 5) * TS;   // 32x32 tiles over the 512^2 half-res grid
    int B0 = (blockIdx.x & 31) * TS;

    // ---- tile+halo val/vor (324 cells; threads 0..67 do a second cell)
    const float SCALE = 512.0f / 511.0f;   // linspace(0, 512, 512) step
    for (int idx = tid; idx < THS * THS; idx += 256) {
        int hu = idx / THS, hw = idx - hu * THS;
        int ca = A0 + hu - 1, cb = B0 + hw - 1;
        float vo = 0.f; int jo = 0;
        if (ca >= 0 && ca < HH && cb >= 0 && cb < WW) {
            float xc = (float)cb * SCALE;
            float yr = (float)ca * SCALE;
            float best = 3.4e38f; int bj = 0;
            #pragma unroll 4
            for (int j = 0; j < NJ; ++j) {
                float4 p = lp[j];
                float ic = lic[j];
                float dx = xc - p.x;
                float dy = yr - p.y;
                // identical expression shape to validated rounds
                float q = p.z * dx * dx + p.w * dx * dy + ic * dy * dy;
                if (q < best) { best = q; bj = j; }   // first index on ties
            }
            vo = expf(-0.5f * best); jo = bj;
        }
        tval[hu][hw] = vo; tvor[hu][hw] = jo;
    }
    __syncthreads();

    // ---- quad-per-thread markers, all from LDS
    int u = tid >> 4, v = tid & 15;
    int a = A0 + u, b = B0 + v;
    bool aM = a > 0, aP = a < 511, bM = b > 0, bP = b < 511;
    int hmm_ = (aM && bM) ? tvor[u    ][v    ] : 0;
    int hm0_ =  aM        ? tvor[u    ][v + 1] : 0;
    int hm1_ = (aM && bP) ? tvor[u    ][v + 2] : 0;
    int h0m_ =  bM        ? tvor[u + 1][v    ] : 0;
    int h00_ =              tvor[u + 1][v + 1];
    int h0p_ =  bP        ? tvor[u + 1][v + 2] : 0;
    int hpm_ = (aP && bM) ? tvor[u + 2][v    ] : 0;
    int hp0_ =  aP        ? tvor[u + 2][v + 1] : 0;
    int hpp_ = (aP && bP) ? tvor[u + 2][v + 2] : 0;
    // exact-int Laplacian (3x3 ones, center -8, zero-padded) per full-res pixel
    int lap00 = -5 * h00_ + hmm_ + 2 * hm0_ + 2 * h0m_;
    int lap01 = -5 * h00_ + 2 * hm0_ + hm1_ + 2 * h0p_;
    int lap10 = -5 * h00_ + 2 * h0m_ + hpm_ + 2 * hp0_;
    int lap11 = -5 * h00_ + 2 * h0p_ + 2 * hp0_ + hpp_;
    int hv = h00_;
    float  pt = lpt[hv], nt = lnt[hv];
    float4 Vv = lvv[hv];
    float2 mv = lmu[hv];
    float m0 = -1.f, m1 = -1.f;   // r0,r1 >= 0, so -1 == "no valid pixel yet"

#define DO_PIXEL(U, V, LAP) {                                                  \
    int i = 2 * a + (U), jx = 2 * b + (V);                                     \
    float ry = ((float)i  * 511.0f) / 1023.0f;                                 \
    float rx = ((float)jx * 511.0f) / 1023.0f;                                 \
    int y0 = (int)ry; int y1 = min(y0 + 1, 511); float wy = ry - (float)y0;    \
    int x0 = (int)rx; int x1 = min(x0 + 1, 511); float wx = rx - (float)x0;    \
    int ly0 = y0 - A0 + 1, ly1 = y1 - A0 + 1;                                  \
    int lx0 = x0 - B0 + 1, lx1 = x1 - B0 + 1;                                  \
    float top = tval[ly0][lx0] * (1.f - wx) + tval[ly0][lx1] * wx;             \
    float bot = tval[ly1][lx0] * (1.f - wx) + tval[ly1][lx1] * wx;             \
    float vf  = top * (1.f - wy) + bot * wy;                                   \
    int mk = hv + 1;                                                           \
    if (vf < pt)     mk = 0;                                                   \
    if (vf < nt)     mk = NJ + 1;                                              \
    if ((LAP) != 0)  mk = NJ + 1;                                              \
    if (mk >= 1 && mk <= NJ) {                                                 \
        float dx = (float)jx - mv.x, dy = (float)i - mv.y;                     \
        float r0 = fabsf(Vv.x * dx + Vv.y * dy);                               \
        float r1 = fabsf(Vv.z * dx + Vv.w * dy);                               \
        m0 = fmaxf(m0, r0); m1 = fmaxf(m1, r1);                                \
    } }

    DO_PIXEL(0, 0, lap00)
    DO_PIXEL(0, 1, lap01)
    DO_PIXEL(1, 0, lap10)
    DO_PIXEL(1, 1, lap11)
#undef DO_PIXEL

    // ---- wave segmented prefix-max over contiguous equal-inst runs
    int lane = tid & 63;
    int inst = (m0 >= 0.f) ? hv : -1;
    #pragma unroll
    for (int d = 1; d < 64; d <<= 1) {
        int   oi = __shfl_up(inst, d);
        float o0 = __shfl_up(m0, d);
        float o1 = __shfl_up(m1, d);
        if (lane >= d && oi == inst) { m0 = fmaxf(m0, o0); m1 = fmaxf(m1, o1); }
    }
    int ni = __shfl_down(inst, 1);
    bool leader = (inst >= 0) && (lane == 63 || ni != inst);
    if (leader) {   // device-scope atomics: coherent across XCDs
        atomicMax(&gm[inst],      __float_as_uint(m0));
        atomicMax(&gm[NJ + inst], __float_as_uint(m1));
        atomicOr (&cnt[inst], 1u);
    }

    // ---- last-block-done: __syncthreads drains vmcnt, so this block's atomics
    // are at the coherence point before tid0 increments the counter.
    __syncthreads();
    if (tid == 0) {
        unsigned done = atomicAdd(bar, 1u);
        isLast = (done == gridDim.x - 1) ? 1 : 0;
    }
    __syncthreads();
    if (!isLast) return;

    // ---------------- loss phase (validated round 5; whole block in barriers)
    if (tid < NJ) {
        float ls0 = lls0[tid], ls1 = lls1[tid];
        float g0 = __uint_as_float(atomicMax(&gm[tid], 0u));        // coherent read
        float g1 = __uint_as_float(atomicMax(&gm[NJ + tid], 0u));
        unsigned has = atomicAdd(&cnt[tid], 0u);
        float lt0 = has ? g0 * g0 : ls0;
        float lt1 = has ? g1 * g1 : ls1;
        float whr = (ls0 + ls1) + (lt0 + lt1);
        float tr  = ls0 * lt0 + ls1 * lt1;
        float det_sqrt = sqrtf(fmaxf((ls0 * ls1) * (lt0 * lt1), FEPS));
        whr = whr - 2.f * sqrtf(fmaxf(tr + 2.f * det_sqrt, FEPS));
        float dist = sqrtf(fmaxf(whr, FEPS));
        float scale = 2.f * fmaxf(sqrtf(fmaxf(sqrtf(fmaxf(det_sqrt, FEPS)), FEPS)), FEPS);
        dist = dist / scale;
        float li = 1.f - 1.f / (1.f + log1pf(dist));
        lb[tid] = li;
        sv[tid] = li;
    }
    __syncthreads();

    // total sum (tree over LDS)
    #pragma unroll
    for (int s = 64; s > 0; s >>= 1) {
        if (tid < s) sv[tid] += sv[tid + s];
        __syncthreads();
    }
    float total = sv[0];
    __syncthreads();

    // 6 largest (keep 122 smallest = ceil(128*0.95))
    float topsum = 0.f;
    #pragma unroll
    for (int it = 0; it < 6; ++it) {
        if (tid < NJ) { sv[tid] = lb[tid]; si[tid] = tid; }
        __syncthreads();
        #pragma unroll
        for (int s = 64; s > 0; s >>= 1) {
            if (tid < s) {
                if (sv[tid + s] > sv[tid]) { sv[tid] = sv[tid + s]; si[tid] = si[tid + s]; }
            }
            __syncthreads();
        }
        topsum += sv[0];
        if (tid == 0) lb[si[0]] = -3.4e38f;
        __syncthreads();
    }

    if (tid == 0) out[0] = 1.0f * (total - topsum) / 122.f;   // LOSS_WEIGHT = 1
}

// ---------------------------------------------------------------- launch
extern "C" void kernel_launch(void* const* d_in, const int* in_sizes, int n_in,
                              void* d_out, int out_size, void* d_ws, size_t ws_size,
                              hipStream_t stream) {
    const float* mu        = (const float*)d_in[0];
    const float* sigma     = (const float*)d_in[1];
    const int*   label     = (const int*)d_in[2];
    // d_in[3] = image: unused by the reference's forward pass
    const float* pos_thres = (const float*)d_in[4];
    const float* neg_thres = (const float*)d_in[5];
    float* out = (float*)d_out;

    // workspace: gm[2*NJ] | cnt[NJ] | bar[1]
    unsigned* g   = (unsigned*)d_ws;
    unsigned* gm  = g;
    unsigned* cnt = g + 2 * NJ;
    unsigned* bar = g + 3 * NJ;

    k_init <<<1, 512, 0, stream>>>(g);
    k_fused<<<32 * 32, 256, 0, stream>>>(mu, sigma, label, pos_thres, neg_thres,
                                         gm, cnt, bar, out);
}

// Round 7
// 64.693 us; speedup vs baseline: 1.0023x; 1.0023x over previous
//
#include <hip/hip_runtime.h>
#include <math.h>

#define NJ 128
#define HH 512
#define WW 512
#define FEPS 1e-7f
#define THS 18     // 16x16 quad tile + 1-cell halo
#define TLP 20     // padded LDS row pitch

// ---------------------------------------------------------------- eig helper
// 2x2 symmetric eigendecomposition, ascending order (matches jnp.linalg.eigh).
// Bit-identical to validated rounds 2-6.
__device__ __forceinline__ void eig2x2(float a, float b, float c,
                                       float& l0, float& l1,
                                       float& V00, float& V10, float& V01, float& V11) {
    float mean = 0.5f * (a + c);
    float diff = 0.5f * (a - c);
    float disc = sqrtf(diff * diff + b * b);
    l0 = mean - disc;   // smaller
    l1 = mean + disc;   // larger
    float ux, uy;
    if (diff >= 0.f) { ux = diff + disc; uy = b; }
    else             { ux = b;           uy = disc - diff; }
    float nn = sqrtf(ux * ux + uy * uy);
    if (nn > 0.f) { ux /= nn; uy /= nn; } else { ux = 1.f; uy = 0.f; }
    V00 = -uy; V10 = ux;   // column 0 (l0)
    V01 =  ux; V11 = uy;   // column 1 (l1)
}

// ---------------------------------------------------------------- K1: setup-in-LDS + vor
// VERBATIM round 5 (measured ~2 us). Params in LDS, float4 broadcast reads,
// 2 pixels/thread sharing dx. Block 0 also inits gm/cnt/bar (stream-ordered
// before K2).
__global__ __launch_bounds__(256, 2) void k_vorf(
        const float* __restrict__ mu, const float* __restrict__ sigma,
        float* __restrict__ val, int* __restrict__ vor,
        unsigned* __restrict__ gm, unsigned* __restrict__ cnt,
        unsigned* __restrict__ bar) {
    __shared__ float4 lp[NJ];   // mmx, mmy, ia, ib2
    __shared__ float  lic[NJ];  // ic
    int tid = threadIdx.x;
    if (tid < NJ) {
        int j = tid;
        float a = sigma[j * 4 + 0];
        float b = sigma[j * 4 + 1];
        float c = sigma[j * 4 + 3];
        float l0, l1, V00, V10, V01, V11;
        eig2x2(a, b, c, l0, l1, V00, V10, V01, V11);
        float gmean = sqrtf(l0 * l1);
        float lsc0 = l0 / gmean * 4096.f;
        float lsc1 = l1 / gmean * 4096.f;
        float s00 = (V00 * V00 * lsc0 + V01 * V01 * lsc1) * 0.25f;
        float s01 = (V00 * V10 * lsc0 + V01 * V11 * lsc1) * 0.25f;
        float s11 = (V10 * V10 * lsc0 + V11 * V11 * lsc1) * 0.25f;
        float det = s00 * s11 - s01 * s01;
        float4 q;
        q.x = rintf(mu[j * 2 + 0] * 0.5f);   // jnp.round = ties-to-even = rintf
        q.y = rintf(mu[j * 2 + 1] * 0.5f);
        q.z =  s11 / det;                    // ia
        q.w = -2.f * s01 / det;              // ib2
        lp[j]  = q;
        lic[j] = s00 / det;                  // ic
    }
    if (blockIdx.x == 0) {                   // init cross-kernel state
        if (tid < NJ) { gm[tid] = 0u; gm[NJ + tid] = 0u; cnt[tid] = 0u; }
        if (tid == 0) *bar = 0u;
    }
    __syncthreads();

    int t = blockIdx.x * 256 + tid;          // 0..131071
    int c = t & 511;
    int r = t >> 9;                          // 0..255
    const float SCALE = 512.0f / 511.0f;     // linspace(0, 512, 512) step
    float xc = (float)c * SCALE;
    float ya = (float)r * SCALE;
    float yb = (float)(r + 256) * SCALE;
    float bestA = 3.4e38f, bestB = 3.4e38f;
    int bjA = 0, bjB = 0;
    #pragma unroll 4
    for (int j = 0; j < NJ; ++j) {
        float4 p = lp[j];
        float ic = lic[j];
        float dx  = xc - p.x;
        float dyA = ya - p.y;
        float dyB = yb - p.y;
        float qA = p.z * dx * dx + p.w * dx * dyA + ic * dyA * dyA;
        float qB = p.z * dx * dx + p.w * dx * dyB + ic * dyB * dyB;
        if (qA < bestA) { bestA = qA; bjA = j; }   // first index on ties
        if (qB < bestB) { bestB = qB; bjB = j; }
    }
    int pA = r * WW + c, pB = (r + 256) * WW + c;
    val[pA] = expf(-0.5f * bestA); vor[pA] = bjA;
    val[pB] = expf(-0.5f * bestB); vor[pB] = bjB;
}

// ---------------------------------------------------------------- K2: tiled markers + loss
// Stage the 18x18 val/vor halo tile into LDS with coalesced loads (replaces
// round 5's ~25 scattered loads/thread), then round 6's validated LDS marker
// phase verbatim, shuffle segmented-max -> leader device-scope atomics, and
// the last-finished block computes the loss.
__global__ __launch_bounds__(256, 2) void k_markt(
        const float* __restrict__ mu, const float* __restrict__ sigma,
        const int* __restrict__ label, const float* __restrict__ pos_thres,
        const float* __restrict__ neg_thres,
        const float* __restrict__ val, const int* __restrict__ vor,
        unsigned* __restrict__ gm, unsigned* __restrict__ cnt,
        unsigned* __restrict__ bar, float* __restrict__ out) {
    __shared__ float4 lvv[NJ];    // V00, V10, V01, V11
    __shared__ float2 lmu[NJ];    // mux, muy
    __shared__ float  lpt[NJ], lnt[NJ];
    __shared__ float  lls0[NJ], lls1[NJ];
    __shared__ float  tval[THS][TLP];
    __shared__ int    tvor[THS][TLP];
    __shared__ float  lb[NJ], sv[NJ];
    __shared__ int    si[NJ];
    __shared__ int    isLast;

    int tid = threadIdx.x;
    // per-block instance tables (identical arithmetic -> identical bits)
    if (tid < NJ) {
        int j = tid;
        float a = sigma[j * 4 + 0];
        float b = sigma[j * 4 + 1];
        float cc = sigma[j * 4 + 3];
        float l0, l1, V00, V10, V01, V11;
        eig2x2(a, b, cc, l0, l1, V00, V10, V01, V11);
        lvv[j] = make_float4(V00, V10, V01, V11);
        lmu[j] = make_float2(mu[j * 2 + 0], mu[j * 2 + 1]);
        int cl = label[j];
        lpt[j] = pos_thres[cl];
        lnt[j] = neg_thres[cl];
        lls0[j] = l0; lls1[j] = l1;
    }

    int A0 = (blockIdx.x >> 5) * 16;   // 32x32 tiles of 16x16 quads
    int B0 = (blockIdx.x & 31) * 16;

    // ---- stage 18x18 halo tile (coalesced rows of 18; OOB -> 0/0)
    for (int idx = tid; idx < THS * THS; idx += 256) {
        int hu = idx / THS, hw = idx - hu * THS;
        int gy = A0 + hu - 1, gx = B0 + hw - 1;
        float vv = 0.f; int jv = 0;
        if (gy >= 0 && gy < HH && gx >= 0 && gx < WW) {
            int g = gy * WW + gx;
            vv = val[g]; jv = vor[g];
        }
        tval[hu][hw] = vv; tvor[hu][hw] = jv;
    }
    __syncthreads();

    // ---- quad-per-thread markers, all from LDS (round 6 verbatim)
    int u = tid >> 4, v = tid & 15;
    int a = A0 + u, b = B0 + v;
    bool aM = a > 0, aP = a < 511, bM = b > 0, bP = b < 511;
    int hmm_ = (aM && bM) ? tvor[u    ][v    ] : 0;
    int hm0_ =  aM        ? tvor[u    ][v + 1] : 0;
    int hm1_ = (aM && bP) ? tvor[u    ][v + 2] : 0;
    int h0m_ =  bM        ? tvor[u + 1][v    ] : 0;
    int h00_ =              tvor[u + 1][v + 1];
    int h0p_ =  bP        ? tvor[u + 1][v + 2] : 0;
    int hpm_ = (aP && bM) ? tvor[u + 2][v    ] : 0;
    int hp0_ =  aP        ? tvor[u + 2][v + 1] : 0;
    int hpp_ = (aP && bP) ? tvor[u + 2][v + 2] : 0;
    // exact-int Laplacian (3x3 ones, center -8, zero-padded) per full-res pixel
    int lap00 = -5 * h00_ + hmm_ + 2 * hm0_ + 2 * h0m_;
    int lap01 = -5 * h00_ + 2 * hm0_ + hm1_ + 2 * h0p_;
    int lap10 = -5 * h00_ + 2 * h0m_ + hpm_ + 2 * hp0_;
    int lap11 = -5 * h00_ + 2 * h0p_ + 2 * hp0_ + hpp_;
    int hv = h00_;
    float  pt = lpt[hv], nt = lnt[hv];
    float4 Vv = lvv[hv];
    float2 mv = lmu[hv];
    float m0 = -1.f, m1 = -1.f;   // r0,r1 >= 0, so -1 == "no valid pixel yet"

#define DO_PIXEL(U, V, LAP) {                                                  \
    int i = 2 * a + (U), jx = 2 * b + (V);                                     \
    float ry = ((float)i  * 511.0f) / 1023.0f;                                 \
    float rx = ((float)jx * 511.0f) / 1023.0f;                                 \
    int y0 = (int)ry; int y1 = min(y0 + 1, 511); float wy = ry - (float)y0;    \
    int x0 = (int)rx; int x1 = min(x0 + 1, 511); float wx = rx - (float)x0;    \
    int ly0 = y0 - A0 + 1, ly1 = y1 - A0 + 1;                                  \
    int lx0 = x0 - B0 + 1, lx1 = x1 - B0 + 1;                                  \
    float top = tval[ly0][lx0] * (1.f - wx) + tval[ly0][lx1] * wx;             \
    float bot = tval[ly1][lx0] * (1.f - wx) + tval[ly1][lx1] * wx;             \
    float vf  = top * (1.f - wy) + bot * wy;                                   \
    int mk = hv + 1;                                                           \
    if (vf < pt)     mk = 0;                                                   \
    if (vf < nt)     mk = NJ + 1;                                              \
    if ((LAP) != 0)  mk = NJ + 1;                                              \
    if (mk >= 1 && mk <= NJ) {                                                 \
        float dx = (float)jx - mv.x, dy = (float)i - mv.y;                     \
        float r0 = fabsf(Vv.x * dx + Vv.y * dy);                               \
        float r1 = fabsf(Vv.z * dx + Vv.w * dy);                               \
        m0 = fmaxf(m0, r0); m1 = fmaxf(m1, r1);                                \
    } }

    DO_PIXEL(0, 0, lap00)
    DO_PIXEL(0, 1, lap01)
    DO_PIXEL(1, 0, lap10)
    DO_PIXEL(1, 1, lap11)
#undef DO_PIXEL

    // ---- wave segmented prefix-max over contiguous equal-inst runs
    int lane = tid & 63;
    int inst = (m0 >= 0.f) ? hv : -1;
    #pragma unroll
    for (int d = 1; d < 64; d <<= 1) {
        int   oi = __shfl_up(inst, d);
        float o0 = __shfl_up(m0, d);
        float o1 = __shfl_up(m1, d);
        if (lane >= d && oi == inst) { m0 = fmaxf(m0, o0); m1 = fmaxf(m1, o1); }
    }
    int ni = __shfl_down(inst, 1);
    bool leader = (inst >= 0) && (lane == 63 || ni != inst);
    if (leader) {   // device-scope atomics: coherent across XCDs
        atomicMax(&gm[inst],      __float_as_uint(m0));
        atomicMax(&gm[NJ + inst], __float_as_uint(m1));
        atomicOr (&cnt[inst], 1u);
    }

    // ---- last-block-done (validated rounds 5-6)
    __syncthreads();
    if (tid == 0) {
        unsigned done = atomicAdd(bar, 1u);
        isLast = (done == gridDim.x - 1) ? 1 : 0;
    }
    __syncthreads();
    if (!isLast) return;

    // ---------------- loss phase (validated rounds 5-6, verbatim)
    if (tid < NJ) {
        float ls0 = lls0[tid], ls1 = lls1[tid];
        float g0 = __uint_as_float(atomicMax(&gm[tid], 0u));        // coherent read
        float g1 = __uint_as_float(atomicMax(&gm[NJ + tid], 0u));
        unsigned has = atomicAdd(&cnt[tid], 0u);
        float lt0 = has ? g0 * g0 : ls0;
        float lt1 = has ? g1 * g1 : ls1;
        float whr = (ls0 + ls1) + (lt0 + lt1);
        float tr  = ls0 * lt0 + ls1 * lt1;
        float det_sqrt = sqrtf(fmaxf((ls0 * ls1) * (lt0 * lt1), FEPS));
        whr = whr - 2.f * sqrtf(fmaxf(tr + 2.f * det_sqrt, FEPS));
        float dist = sqrtf(fmaxf(whr, FEPS));
        float scale = 2.f * fmaxf(sqrtf(fmaxf(sqrtf(fmaxf(det_sqrt, FEPS)), FEPS)), FEPS);
        dist = dist / scale;
        float li = 1.f - 1.f / (1.f + log1pf(dist));
        lb[tid] = li;
        sv[tid] = li;
    }
    __syncthreads();

    // total sum (tree over LDS)
    #pragma unroll
    for (int s = 64; s > 0; s >>= 1) {
        if (tid < s) sv[tid] += sv[tid + s];
        __syncthreads();
    }
    float total = sv[0];
    __syncthreads();

    // 6 largest (keep 122 smallest = ceil(128*0.95))
    float topsum = 0.f;
    #pragma unroll
    for (int it = 0; it < 6; ++it) {
        if (tid < NJ) { sv[tid] = lb[tid]; si[tid] = tid; }
        __syncthreads();
        #pragma unroll
        for (int s = 64; s > 0; s >>= 1) {
            if (tid < s) {
                if (sv[tid + s] > sv[tid]) { sv[tid] = sv[tid + s]; si[tid] = si[tid + s]; }
            }
            __syncthreads();
        }
        topsum += sv[0];
        if (tid == 0) lb[si[0]] = -3.4e38f;
        __syncthreads();
    }

    if (tid == 0) out[0] = 1.0f * (total - topsum) / 122.f;   // LOSS_WEIGHT = 1
}

// ---------------------------------------------------------------- launch
extern "C" void kernel_launch(void* const* d_in, const int* in_sizes, int n_in,
                              void* d_out, int out_size, void* d_ws, size_t ws_size,
                              hipStream_t stream) {
    const float* mu        = (const float*)d_in[0];
    const float* sigma     = (const float*)d_in[1];
    const int*   label     = (const int*)d_in[2];
    // d_in[3] = image: unused by the reference's forward pass
    const float* pos_thres = (const float*)d_in[4];
    const float* neg_thres = (const float*)d_in[5];
    float* out = (float*)d_out;

    // workspace layout
    float*    val = (float*)d_ws;                                   // 512*512 f32 (1 MiB)
    int*      vor = (int*)((char*)d_ws + (size_t)HH * WW * 4);      // 512*512 i32 (1 MiB)
    unsigned* gm  = (unsigned*)((char*)d_ws + 2ull * HH * WW * 4);  // 2*NJ u32
    unsigned* cnt = gm + 2 * NJ;                                    // NJ u32
    unsigned* bar = cnt + NJ;                                       // 1 u32

    k_vorf <<<(HH * WW / 2) / 256, 256, 0, stream>>>(mu, sigma, val, vor, gm, cnt, bar);
    k_markt<<<(HH * WW) / 256, 256, 0, stream>>>(mu, sigma, label, pos_thres, neg_thres,
                                                 val, vor, gm, cnt, bar, out);
}

// Round 8
// 63.626 us; speedup vs baseline: 1.0191x; 1.0168x over previous
//
#include <hip/hip_runtime.h>
#include <math.h>

#define NJ 128
#define HH 512
#define WW 512
#define FEPS 1e-7f
#define THS 18     // 16x16 quad tile + 1-cell halo
#define TLP 20     // padded LDS row pitch

// ---------------------------------------------------------------- eig helper
// 2x2 symmetric eigendecomposition, ascending order (matches jnp.linalg.eigh).
// Bit-identical to validated rounds 2-6.
__device__ __forceinline__ void eig2x2(float a, float b, float c,
                                       float& l0, float& l1,
                                       float& V00, float& V10, float& V01, float& V11) {
    float mean = 0.5f * (a + c);
    float diff = 0.5f * (a - c);
    float disc = sqrtf(diff * diff + b * b);
    l0 = mean - disc;   // smaller
    l1 = mean + disc;   // larger
    float ux, uy;
    if (diff >= 0.f) { ux = diff + disc; uy = b; }
    else             { ux = b;           uy = disc - diff; }
    float nn = sqrtf(ux * ux + uy * uy);
    if (nn > 0.f) { ux /= nn; uy /= nn; } else { ux = 1.f; uy = 0.f; }
    V00 = -uy; V10 = ux;   // column 0 (l0)
    V01 =  ux; V11 = uy;   // column 1 (l1)
}

// ---------------------------------------------------------------- K1: setup-in-LDS + vor
// VERBATIM round 5 (measured ~2 us). Params in LDS, float4 broadcast reads,
// 2 pixels/thread sharing dx. Block 0 also inits gm/cnt/bar (stream-ordered
// before K2).
__global__ __launch_bounds__(256, 2) void k_vorf(
        const float* __restrict__ mu, const float* __restrict__ sigma,
        float* __restrict__ val, int* __restrict__ vor,
        unsigned* __restrict__ gm, unsigned* __restrict__ cnt,
        unsigned* __restrict__ bar) {
    __shared__ float4 lp[NJ];   // mmx, mmy, ia, ib2
    __shared__ float  lic[NJ];  // ic
    int tid = threadIdx.x;
    if (tid < NJ) {
        int j = tid;
        float a = sigma[j * 4 + 0];
        float b = sigma[j * 4 + 1];
        float c = sigma[j * 4 + 3];
        float l0, l1, V00, V10, V01, V11;
        eig2x2(a, b, c, l0, l1, V00, V10, V01, V11);
        float gmean = sqrtf(l0 * l1);
        float lsc0 = l0 / gmean * 4096.f;
        float lsc1 = l1 / gmean * 4096.f;
        float s00 = (V00 * V00 * lsc0 + V01 * V01 * lsc1) * 0.25f;
        float s01 = (V00 * V10 * lsc0 + V01 * V11 * lsc1) * 0.25f;
        float s11 = (V10 * V10 * lsc0 + V11 * V11 * lsc1) * 0.25f;
        float det = s00 * s11 - s01 * s01;
        float4 q;
        q.x = rintf(mu[j * 2 + 0] * 0.5f);   // jnp.round = ties-to-even = rintf
        q.y = rintf(mu[j * 2 + 1] * 0.5f);
        q.z =  s11 / det;                    // ia
        q.w = -2.f * s01 / det;              // ib2
        lp[j]  = q;
        lic[j] = s00 / det;                  // ic
    }
    if (blockIdx.x == 0) {                   // init cross-kernel state
        if (tid < NJ) { gm[tid] = 0u; gm[NJ + tid] = 0u; cnt[tid] = 0u; }
        if (tid == 0) *bar = 0u;
    }
    __syncthreads();

    int t = blockIdx.x * 256 + tid;          // 0..131071
    int c = t & 511;
    int r = t >> 9;                          // 0..255
    const float SCALE = 512.0f / 511.0f;     // linspace(0, 512, 512) step
    float xc = (float)c * SCALE;
    float ya = (float)r * SCALE;
    float yb = (float)(r + 256) * SCALE;
    float bestA = 3.4e38f, bestB = 3.4e38f;
    int bjA = 0, bjB = 0;
    #pragma unroll 4
    for (int j = 0; j < NJ; ++j) {
        float4 p = lp[j];
        float ic = lic[j];
        float dx  = xc - p.x;
        float dyA = ya - p.y;
        float dyB = yb - p.y;
        float qA = p.z * dx * dx + p.w * dx * dyA + ic * dyA * dyA;
        float qB = p.z * dx * dx + p.w * dx * dyB + ic * dyB * dyB;
        if (qA < bestA) { bestA = qA; bjA = j; }   // first index on ties
        if (qB < bestB) { bestB = qB; bjB = j; }
    }
    int pA = r * WW + c, pB = (r + 256) * WW + c;
    val[pA] = expf(-0.5f * bestA); vor[pA] = bjA;
    val[pB] = expf(-0.5f * bestB); vor[pB] = bjB;
}

// ---------------------------------------------------------------- K2: tiled markers + loss
// Stage the 18x18 val/vor halo tile into LDS with coalesced loads (replaces
// round 5's ~25 scattered loads/thread), then round 6's validated LDS marker
// phase verbatim, shuffle segmented-max -> leader device-scope atomics, and
// the last-finished block computes the loss.
__global__ __launch_bounds__(256, 2) void k_markt(
        const float* __restrict__ mu, const float* __restrict__ sigma,
        const int* __restrict__ label, const float* __restrict__ pos_thres,
        const float* __restrict__ neg_thres,
        const float* __restrict__ val, const int* __restrict__ vor,
        unsigned* __restrict__ gm, unsigned* __restrict__ cnt,
        unsigned* __restrict__ bar, float* __restrict__ out) {
    __shared__ float4 lvv[NJ];    // V00, V10, V01, V11
    __shared__ float2 lmu[NJ];    // mux, muy
    __shared__ float  lpt[NJ], lnt[NJ];
    __shared__ float  lls0[NJ], lls1[NJ];
    __shared__ float  tval[THS][TLP];
    __shared__ int    tvor[THS][TLP];
    __shared__ float  lb[NJ], sv[NJ];
    __shared__ int    si[NJ];
    __shared__ int    isLast;

    int tid = threadIdx.x;
    // per-block instance tables (identical arithmetic -> identical bits)
    if (tid < NJ) {
        int j = tid;
        float a = sigma[j * 4 + 0];
        float b = sigma[j * 4 + 1];
        float cc = sigma[j * 4 + 3];
        float l0, l1, V00, V10, V01, V11;
        eig2x2(a, b, cc, l0, l1, V00, V10, V01, V11);
        lvv[j] = make_float4(V00, V10, V01, V11);
        lmu[j] = make_float2(mu[j * 2 + 0], mu[j * 2 + 1]);
        int cl = label[j];
        lpt[j] = pos_thres[cl];
        lnt[j] = neg_thres[cl];
        lls0[j] = l0; lls1[j] = l1;
    }

    int A0 = (blockIdx.x >> 5) * 16;   // 32x32 tiles of 16x16 quads
    int B0 = (blockIdx.x & 31) * 16;

    // ---- stage 18x18 halo tile (coalesced rows of 18; OOB -> 0/0)
    for (int idx = tid; idx < THS * THS; idx += 256) {
        int hu = idx / THS, hw = idx - hu * THS;
        int gy = A0 + hu - 1, gx = B0 + hw - 1;
        float vv = 0.f; int jv = 0;
        if (gy >= 0 && gy < HH && gx >= 0 && gx < WW) {
            int g = gy * WW + gx;
            vv = val[g]; jv = vor[g];
        }
        tval[hu][hw] = vv; tvor[hu][hw] = jv;
    }
    __syncthreads();

    // ---- quad-per-thread markers, all from LDS (round 6 verbatim)
    int u = tid >> 4, v = tid & 15;
    int a = A0 + u, b = B0 + v;
    bool aM = a > 0, aP = a < 511, bM = b > 0, bP = b < 511;
    int hmm_ = (aM && bM) ? tvor[u    ][v    ] : 0;
    int hm0_ =  aM        ? tvor[u    ][v + 1] : 0;
    int hm1_ = (aM && bP) ? tvor[u    ][v + 2] : 0;
    int h0m_ =  bM        ? tvor[u + 1][v    ] : 0;
    int h00_ =              tvor[u + 1][v + 1];
    int h0p_ =  bP        ? tvor[u + 1][v + 2] : 0;
    int hpm_ = (aP && bM) ? tvor[u + 2][v    ] : 0;
    int hp0_ =  aP        ? tvor[u + 2][v + 1] : 0;
    int hpp_ = (aP && bP) ? tvor[u + 2][v + 2] : 0;
    // exact-int Laplacian (3x3 ones, center -8, zero-padded) per full-res pixel
    int lap00 = -5 * h00_ + hmm_ + 2 * hm0_ + 2 * h0m_;
    int lap01 = -5 * h00_ + 2 * hm0_ + hm1_ + 2 * h0p_;
    int lap10 = -5 * h00_ + 2 * h0m_ + hpm_ + 2 * hp0_;
    int lap11 = -5 * h00_ + 2 * h0p_ + 2 * hp0_ + hpp_;
    int hv = h00_;
    float  pt = lpt[hv], nt = lnt[hv];
    float4 Vv = lvv[hv];
    float2 mv = lmu[hv];
    float m0 = -1.f, m1 = -1.f;   // r0,r1 >= 0, so -1 == "no valid pixel yet"

#define DO_PIXEL(U, V, LAP) {                                                  \
    int i = 2 * a + (U), jx = 2 * b + (V);                                     \
    float ry = ((float)i  * 511.0f) / 1023.0f;                                 \
    float rx = ((float)jx * 511.0f) / 1023.0f;                                 \
    int y0 = (int)ry; int y1 = min(y0 + 1, 511); float wy = ry - (float)y0;    \
    int x0 = (int)rx; int x1 = min(x0 + 1, 511); float wx = rx - (float)x0;    \
    int ly0 = y0 - A0 + 1, ly1 = y1 - A0 + 1;                                  \
    int lx0 = x0 - B0 + 1, lx1 = x1 - B0 + 1;                                  \
    float top = tval[ly0][lx0] * (1.f - wx) + tval[ly0][lx1] * wx;             \
    float bot = tval[ly1][lx0] * (1.f - wx) + tval[ly1][lx1] * wx;             \
    float vf  = top * (1.f - wy) + bot * wy;                                   \
    int mk = hv + 1;                                                           \
    if (vf < pt)     mk = 0;                                                   \
    if (vf < nt)     mk = NJ + 1;                                              \
    if ((LAP) != 0)  mk = NJ + 1;                                              \
    if (mk >= 1 && mk <= NJ) {                                                 \
        float dx = (float)jx - mv.x, dy = (float)i - mv.y;                     \
        float r0 = fabsf(Vv.x * dx + Vv.y * dy);                               \
        float r1 = fabsf(Vv.z * dx + Vv.w * dy);                               \
        m0 = fmaxf(m0, r0); m1 = fmaxf(m1, r1);                                \
    } }

    DO_PIXEL(0, 0, lap00)
    DO_PIXEL(0, 1, lap01)
    DO_PIXEL(1, 0, lap10)
    DO_PIXEL(1, 1, lap11)
#undef DO_PIXEL

    // ---- wave segmented prefix-max over contiguous equal-inst runs
    int lane = tid & 63;
    int inst = (m0 >= 0.f) ? hv : -1;
    #pragma unroll
    for (int d = 1; d < 64; d <<= 1) {
        int   oi = __shfl_up(inst, d);
        float o0 = __shfl_up(m0, d);
        float o1 = __shfl_up(m1, d);
        if (lane >= d && oi == inst) { m0 = fmaxf(m0, o0); m1 = fmaxf(m1, o1); }
    }
    int ni = __shfl_down(inst, 1);
    bool leader = (inst >= 0) && (lane == 63 || ni != inst);
    if (leader) {   // device-scope atomics: coherent across XCDs
        atomicMax(&gm[inst],      __float_as_uint(m0));
        atomicMax(&gm[NJ + inst], __float_as_uint(m1));
        atomicOr (&cnt[inst], 1u);
    }

    // ---- last-block-done (validated rounds 5-6)
    __syncthreads();
    if (tid == 0) {
        unsigned done = atomicAdd(bar, 1u);
        isLast = (done == gridDim.x - 1) ? 1 : 0;
    }
    __syncthreads();
    if (!isLast) return;

    // ---------------- loss phase (validated rounds 5-6, verbatim)
    if (tid < NJ) {
        float ls0 = lls0[tid], ls1 = lls1[tid];
        float g0 = __uint_as_float(atomicMax(&gm[tid], 0u));        // coherent read
        float g1 = __uint_as_float(atomicMax(&gm[NJ + tid], 0u));
        unsigned has = atomicAdd(&cnt[tid], 0u);
        float lt0 = has ? g0 * g0 : ls0;
        float lt1 = has ? g1 * g1 : ls1;
        float whr = (ls0 + ls1) + (lt0 + lt1);
        float tr  = ls0 * lt0 + ls1 * lt1;
        float det_sqrt = sqrtf(fmaxf((ls0 * ls1) * (lt0 * lt1), FEPS));
        whr = whr - 2.f * sqrtf(fmaxf(tr + 2.f * det_sqrt, FEPS));
        float dist = sqrtf(fmaxf(whr, FEPS));
        float scale = 2.f * fmaxf(sqrtf(fmaxf(sqrtf(fmaxf(det_sqrt, FEPS)), FEPS)), FEPS);
        dist = dist / scale;
        float li = 1.f - 1.f / (1.f + log1pf(dist));
        lb[tid] = li;
        sv[tid] = li;
    }
    __syncthreads();

    // total sum (tree over LDS)
    #pragma unroll
    for (int s = 64; s > 0; s >>= 1) {
        if (tid < s) sv[tid] += sv[tid + s];
        __syncthreads();
    }
    float total = sv[0];
    __syncthreads();

    // 6 largest (keep 122 smallest = ceil(128*0.95))
    float topsum = 0.f;
    #pragma unroll
    for (int it = 0; it < 6; ++it) {
        if (tid < NJ) { sv[tid] = lb[tid]; si[tid] = tid; }
        __syncthreads();
        #pragma unroll
        for (int s = 64; s > 0; s >>= 1) {
            if (tid < s) {
                if (sv[tid + s] > sv[tid]) { sv[tid] = sv[tid + s]; si[tid] = si[tid + s]; }
            }
            __syncthreads();
        }
        topsum += sv[0];
        if (tid == 0) lb[si[0]] = -3.4e38f;
        __syncthreads();
    }

    if (tid == 0) out[0] = 1.0f * (total - topsum) / 122.f;   // LOSS_WEIGHT = 1
}

// ---------------------------------------------------------------- launch
extern "C" void kernel_launch(void* const* d_in, const int* in_sizes, int n_in,
                              void* d_out, int out_size, void* d_ws, size_t ws_size,
                              hipStream_t stream) {
    const float* mu        = (const float*)d_in[0];
    const float* sigma     = (const float*)d_in[1];
    const int*   label     = (const int*)d_in[2];
    // d_in[3] = image: unused by the reference's forward pass
    const float* pos_thres = (const float*)d_in[4];
    const float* neg_thres = (const float*)d_in[5];
    float* out = (float*)d_out;

    // workspace layout
    float*    val = (float*)d_ws;                                   // 512*512 f32 (1 MiB)
    int*      vor = (int*)((char*)d_ws + (size_t)HH * WW * 4);      // 512*512 i32 (1 MiB)
    unsigned* gm  = (unsigned*)((char*)d_ws + 2ull * HH * WW * 4);  // 2*NJ u32
    unsigned* cnt = gm + 2 * NJ;                                    // NJ u32
    unsigned* bar = cnt + NJ;                                       // 1 u32

    k_vorf <<<(HH * WW / 2) / 256, 256, 0, stream>>>(mu, sigma, val, vor, gm, cnt, bar);
    k_markt<<<(HH * WW) / 256, 256, 0, stream>>>(mu, sigma, label, pos_thres, neg_thres,
                                                 val, vor, gm, cnt, bar, out);
}

// Round 9
// 31.669 us; speedup vs baseline: 2.0474x; 2.0091x over previous
//
#include <hip/hip_runtime.h>
#include <math.h>

#define NJ 128
#define HH 512
#define WW 512
#define FEPS 1e-7f
#define QT  32          // quad tile edge (quads per block side)
#define THS (QT + 2)    // 34: tile + 1-cell halo
#define TLP 36          // padded LDS row pitch

// ---------------------------------------------------------------- eig helper
// 2x2 symmetric eigendecomposition, ascending order (matches jnp.linalg.eigh).
// Bit-identical to validated rounds 2-8.
__device__ __forceinline__ void eig2x2(float a, float b, float c,
                                       float& l0, float& l1,
                                       float& V00, float& V10, float& V01, float& V11) {
    float mean = 0.5f * (a + c);
    float diff = 0.5f * (a - c);
    float disc = sqrtf(diff * diff + b * b);
    l0 = mean - disc;   // smaller
    l1 = mean + disc;   // larger
    float ux, uy;
    if (diff >= 0.f) { ux = diff + disc; uy = b; }
    else             { ux = b;           uy = disc - diff; }
    float nn = sqrtf(ux * ux + uy * uy);
    if (nn > 0.f) { ux /= nn; uy /= nn; } else { ux = 1.f; uy = 0.f; }
    V00 = -uy; V10 = ux;   // column 0 (l0)
    V01 =  ux; V11 = uy;   // column 1 (l1)
}

// ---------------------------------------------------------------- K1: setup-in-LDS + vor
// VERBATIM round 5 (measured ~2 us), except block 0 inits the padded gml table.
__global__ __launch_bounds__(256, 2) void k_vorf(
        const float* __restrict__ mu, const float* __restrict__ sigma,
        float* __restrict__ val, int* __restrict__ vor,
        unsigned* __restrict__ gml) {
    __shared__ float4 lp[NJ];   // mmx, mmy, ia, ib2
    __shared__ float  lic[NJ];  // ic
    int tid = threadIdx.x;
    if (tid < NJ) {
        int j = tid;
        float a = sigma[j * 4 + 0];
        float b = sigma[j * 4 + 1];
        float c = sigma[j * 4 + 3];
        float l0, l1, V00, V10, V01, V11;
        eig2x2(a, b, c, l0, l1, V00, V10, V01, V11);
        float gmean = sqrtf(l0 * l1);
        float lsc0 = l0 / gmean * 4096.f;
        float lsc1 = l1 / gmean * 4096.f;
        float s00 = (V00 * V00 * lsc0 + V01 * V01 * lsc1) * 0.25f;
        float s01 = (V00 * V10 * lsc0 + V01 * V11 * lsc1) * 0.25f;
        float s11 = (V10 * V10 * lsc0 + V11 * V11 * lsc1) * 0.25f;
        float det = s00 * s11 - s01 * s01;
        float4 q;
        q.x = rintf(mu[j * 2 + 0] * 0.5f);   // jnp.round = ties-to-even = rintf
        q.y = rintf(mu[j * 2 + 1] * 0.5f);
        q.z =  s11 / det;                    // ia
        q.w = -2.f * s01 / det;              // ib2
        lp[j]  = q;
        lic[j] = s00 / det;                  // ic
    }
    if (blockIdx.x == 0 && tid < NJ) {       // init padded atomic table (stream-ordered)
        gml[tid * 16 + 0] = 0u;
        gml[tid * 16 + 1] = 0u;
        gml[tid * 16 + 2] = 0u;
    }
    __syncthreads();

    int t = blockIdx.x * 256 + tid;          // 0..131071
    int c = t & 511;
    int r = t >> 9;                          // 0..255
    const float SCALE = 512.0f / 511.0f;     // linspace(0, 512, 512) step
    float xc = (float)c * SCALE;
    float ya = (float)r * SCALE;
    float yb = (float)(r + 256) * SCALE;
    float bestA = 3.4e38f, bestB = 3.4e38f;
    int bjA = 0, bjB = 0;
    #pragma unroll 4
    for (int j = 0; j < NJ; ++j) {
        float4 p = lp[j];
        float ic = lic[j];
        float dx  = xc - p.x;
        float dyA = ya - p.y;
        float dyB = yb - p.y;
        float qA = p.z * dx * dx + p.w * dx * dyA + ic * dyA * dyA;
        float qB = p.z * dx * dx + p.w * dx * dyB + ic * dyB * dyB;
        if (qA < bestA) { bestA = qA; bjA = j; }   // first index on ties
        if (qB < bestB) { bestB = qB; bjB = j; }
    }
    int pA = r * WW + c, pB = (r + 256) * WW + c;
    val[pA] = expf(-0.5f * bestA); vor[pA] = bjA;
    val[pB] = expf(-0.5f * bestB); vor[pB] = bjB;
}

// ---------------------------------------------------------------- K2: tiled markers
// 256 blocks, 32x32-quad tiles, 4 quads/thread in 4 passes. Validated marker
// math verbatim (rounds 6-8). Per pass: shuffle segmented-max -> leaders fold
// into per-block LDS table -> at the end, one global atomic triple per
// TOUCHED instance per BLOCK (~10/block), into 64B-padded lines.
__global__ __launch_bounds__(256) void k_markt(
        const float* __restrict__ mu, const float* __restrict__ sigma,
        const int* __restrict__ label, const float* __restrict__ pos_thres,
        const float* __restrict__ neg_thres,
        const float* __restrict__ val, const int* __restrict__ vor,
        unsigned* __restrict__ gml) {
    __shared__ float4   lvv[NJ];    // V00, V10, V01, V11
    __shared__ float2   lmu[NJ];    // mux, muy
    __shared__ float    lpt[NJ], lnt[NJ];
    __shared__ float    tval[THS][TLP];
    __shared__ int      tvor[THS][TLP];
    __shared__ unsigned lm0[NJ], lm1[NJ];
    __shared__ int      lflag[NJ];

    int tid = threadIdx.x;
    if (tid < NJ) {
        int j = tid;
        float a = sigma[j * 4 + 0];
        float b = sigma[j * 4 + 1];
        float cc = sigma[j * 4 + 3];
        float l0, l1, V00, V10, V01, V11;
        eig2x2(a, b, cc, l0, l1, V00, V10, V01, V11);
        lvv[j] = make_float4(V00, V10, V01, V11);
        lmu[j] = make_float2(mu[j * 2 + 0], mu[j * 2 + 1]);
        int cl = label[j];
        lpt[j] = pos_thres[cl];
        lnt[j] = neg_thres[cl];
        lm0[j] = 0u; lm1[j] = 0u; lflag[j] = 0;
    }

    int A0 = (blockIdx.x >> 4) * QT;   // 16x16 tiles of 32x32 quads
    int B0 = (blockIdx.x & 15) * QT;

    // ---- stage 34x34 halo tile (coalesced rows; OOB -> 0/0, never consumed)
    for (int idx = tid; idx < THS * THS; idx += 256) {
        int hu = idx / THS, hw = idx - hu * THS;
        int gy = A0 + hu - 1, gx = B0 + hw - 1;
        float vv = 0.f; int jv = 0;
        if (gy >= 0 && gy < HH && gx >= 0 && gx < WW) {
            int g = gy * WW + gx;
            vv = val[g]; jv = vor[g];
        }
        tval[hu][hw] = vv; tvor[hu][hw] = jv;
    }
    __syncthreads();

    int lane = tid & 63;
    #pragma unroll
    for (int p = 0; p < 4; ++p) {
        int u = (tid >> 4) + ((p >> 1) << 4);   // 0..31
        int v = (tid & 15) + ((p & 1) << 4);    // 0..31
        int a = A0 + u, b = B0 + v;
        bool aM = a > 0, aP = a < 511, bM = b > 0, bP = b < 511;
        int hmm_ = (aM && bM) ? tvor[u    ][v    ] : 0;
        int hm0_ =  aM        ? tvor[u    ][v + 1] : 0;
        int hm1_ = (aM && bP) ? tvor[u    ][v + 2] : 0;
        int h0m_ =  bM        ? tvor[u + 1][v    ] : 0;
        int h00_ =              tvor[u + 1][v + 1];
        int h0p_ =  bP        ? tvor[u + 1][v + 2] : 0;
        int hpm_ = (aP && bM) ? tvor[u + 2][v    ] : 0;
        int hp0_ =  aP        ? tvor[u + 2][v + 1] : 0;
        int hpp_ = (aP && bP) ? tvor[u + 2][v + 2] : 0;
        // exact-int Laplacian (3x3 ones, center -8, zero-padded) per full-res pixel
        int lap00 = -5 * h00_ + hmm_ + 2 * hm0_ + 2 * h0m_;
        int lap01 = -5 * h00_ + 2 * hm0_ + hm1_ + 2 * h0p_;
        int lap10 = -5 * h00_ + 2 * h0m_ + hpm_ + 2 * hp0_;
        int lap11 = -5 * h00_ + 2 * h0p_ + 2 * hp0_ + hpp_;
        int hv = h00_;
        float  pt = lpt[hv], nt = lnt[hv];
        float4 Vv = lvv[hv];
        float2 mv = lmu[hv];
        float m0 = -1.f, m1 = -1.f;   // r0,r1 >= 0, so -1 == "no valid pixel yet"

#define DO_PIXEL(U, V, LAP) {                                                  \
    int i = 2 * a + (U), jx = 2 * b + (V);                                     \
    float ry = ((float)i  * 511.0f) / 1023.0f;                                 \
    float rx = ((float)jx * 511.0f) / 1023.0f;                                 \
    int y0 = (int)ry; int y1 = min(y0 + 1, 511); float wy = ry - (float)y0;    \
    int x0 = (int)rx; int x1 = min(x0 + 1, 511); float wx = rx - (float)x0;    \
    int ly0 = y0 - A0 + 1, ly1 = y1 - A0 + 1;                                  \
    int lx0 = x0 - B0 + 1, lx1 = x1 - B0 + 1;                                  \
    float top = tval[ly0][lx0] * (1.f - wx) + tval[ly0][lx1] * wx;             \
    float bot = tval[ly1][lx0] * (1.f - wx) + tval[ly1][lx1] * wx;             \
    float vf  = top * (1.f - wy) + bot * wy;                                   \
    int mk = hv + 1;                                                           \
    if (vf < pt)     mk = 0;                                                   \
    if (vf < nt)     mk = NJ + 1;                                              \
    if ((LAP) != 0)  mk = NJ + 1;                                              \
    if (mk >= 1 && mk <= NJ) {                                                 \
        float dx = (float)jx - mv.x, dy = (float)i - mv.y;                     \
        float r0 = fabsf(Vv.x * dx + Vv.y * dy);                               \
        float r1 = fabsf(Vv.z * dx + Vv.w * dy);                               \
        m0 = fmaxf(m0, r0); m1 = fmaxf(m1, r1);                                \
    } }

        DO_PIXEL(0, 0, lap00)
        DO_PIXEL(0, 1, lap01)
        DO_PIXEL(1, 0, lap10)
        DO_PIXEL(1, 1, lap11)
#undef DO_PIXEL

        // wave segmented prefix-max over contiguous equal-inst runs (validated)
        int inst = (m0 >= 0.f) ? hv : -1;
        #pragma unroll
        for (int d = 1; d < 64; d <<= 1) {
            int   oi = __shfl_up(inst, d);
            float o0 = __shfl_up(m0, d);
            float o1 = __shfl_up(m1, d);
            if (lane >= d && oi == inst) { m0 = fmaxf(m0, o0); m1 = fmaxf(m1, o1); }
        }
        int ni = __shfl_down(inst, 1);
        bool leader = (inst >= 0) && (lane == 63 || ni != inst);
        if (leader) {   // few per wave -> cheap LDS atomics, on-CU
            atomicMax(&lm0[inst], __float_as_uint(m0));
            atomicMax(&lm1[inst], __float_as_uint(m1));
            lflag[inst] = 1;    // benign race, same value
        }
    }
    __syncthreads();

    // one global atomic triple per touched instance per block, padded lines
    if (tid < NJ && lflag[tid]) {
        atomicMax(&gml[tid * 16 + 0], lm0[tid]);
        atomicMax(&gml[tid * 16 + 1], lm1[tid]);
        gml[tid * 16 + 2] = 1u;   // benign race, same value; visible at dispatch end
    }
}

// ---------------------------------------------------------------- K3: loss + bottom-122 mean
// Parallel version validated rounds 3-8. Plain reads of gml (stream-ordered
// after K2 completes).
__global__ __launch_bounds__(128) void k_loss(
        const float* __restrict__ sigma, const unsigned* __restrict__ gml,
        float* __restrict__ out) {
    __shared__ float lb[NJ];
    __shared__ float sv[NJ];
    __shared__ int   si[NJ];
    int j = threadIdx.x;

    float aa = sigma[j * 4 + 0];
    float bb = sigma[j * 4 + 1];
    float cc = sigma[j * 4 + 3];
    float ls0, ls1, V00, V10, V01, V11;
    eig2x2(aa, bb, cc, ls0, ls1, V00, V10, V01, V11);
    float g0 = __uint_as_float(gml[j * 16 + 0]);
    float g1 = __uint_as_float(gml[j * 16 + 1]);
    bool has = gml[j * 16 + 2] > 0u;
    float lt0 = has ? g0 * g0 : ls0;
    float lt1 = has ? g1 * g1 : ls1;
    float whr = (ls0 + ls1) + (lt0 + lt1);
    float tr  = ls0 * lt0 + ls1 * lt1;
    float det_sqrt = sqrtf(fmaxf((ls0 * ls1) * (lt0 * lt1), FEPS));
    whr = whr - 2.f * sqrtf(fmaxf(tr + 2.f * det_sqrt, FEPS));
    float dist = sqrtf(fmaxf(whr, FEPS));
    float scale = 2.f * fmaxf(sqrtf(fmaxf(sqrtf(fmaxf(det_sqrt, FEPS)), FEPS)), FEPS);
    dist = dist / scale;
    float li = 1.f - 1.f / (1.f + log1pf(dist));
    lb[j] = li;
    sv[j] = li;
    __syncthreads();

    // total sum (tree over LDS)
    #pragma unroll
    for (int s = 64; s > 0; s >>= 1) {
        if (j < s) sv[j] += sv[j + s];
        __syncthreads();
    }
    float total = sv[0];
    __syncthreads();

    // 6 largest (keep 122 smallest = ceil(128*0.95))
    float topsum = 0.f;
    #pragma unroll
    for (int it = 0; it < 6; ++it) {
        sv[j] = lb[j]; si[j] = j;
        __syncthreads();
        #pragma unroll
        for (int s = 64; s > 0; s >>= 1) {
            if (j < s) {
                if (sv[j + s] > sv[j]) { sv[j] = sv[j + s]; si[j] = si[j + s]; }
            }
            __syncthreads();
        }
        topsum += sv[0];
        if (j == 0) lb[si[0]] = -3.4e38f;
        __syncthreads();
    }

    if (j == 0) out[0] = 1.0f * (total - topsum) / 122.f;   // LOSS_WEIGHT = 1
}

// ---------------------------------------------------------------- launch
extern "C" void kernel_launch(void* const* d_in, const int* in_sizes, int n_in,
                              void* d_out, int out_size, void* d_ws, size_t ws_size,
                              hipStream_t stream) {
    const float* mu        = (const float*)d_in[0];
    const float* sigma     = (const float*)d_in[1];
    const int*   label     = (const int*)d_in[2];
    // d_in[3] = image: unused by the reference's forward pass
    const float* pos_thres = (const float*)d_in[4];
    const float* neg_thres = (const float*)d_in[5];
    float* out = (float*)d_out;

    // workspace layout
    float*    val = (float*)d_ws;                                   // 512*512 f32 (1 MiB)
    int*      vor = (int*)((char*)d_ws + (size_t)HH * WW * 4);      // 512*512 i32 (1 MiB)
    unsigned* gml = (unsigned*)((char*)d_ws + 2ull * HH * WW * 4);  // 128 * 16 u32 (8 KiB, 64B/inst)

    k_vorf <<<(HH * WW / 2) / 256, 256, 0, stream>>>(mu, sigma, val, vor, gml);
    k_markt<<<256, 256, 0, stream>>>(mu, sigma, label, pos_thres, neg_thres,
                                     val, vor, gml);
    k_loss <<<1, 128, 0, stream>>>(sigma, gml, out);
}

// Round 10
// 29.655 us; speedup vs baseline: 2.1865x; 1.0679x over previous
//
#include <hip/hip_runtime.h>
#include <math.h>

#define NJ 128
#define HH 512
#define WW 512
#define FEPS 1e-7f
#define QT  32          // quad tile edge (quads per block side)
#define THS (QT + 2)    // 34: tile + 1-cell halo
#define TLP 36          // padded LDS row pitch

// ---------------------------------------------------------------- eig helper
// 2x2 symmetric eigendecomposition, ascending order (matches jnp.linalg.eigh).
// Bit-identical to validated rounds 2-9.
__device__ __forceinline__ void eig2x2(float a, float b, float c,
                                       float& l0, float& l1,
                                       float& V00, float& V10, float& V01, float& V11) {
    float mean = 0.5f * (a + c);
    float diff = 0.5f * (a - c);
    float disc = sqrtf(diff * diff + b * b);
    l0 = mean - disc;   // smaller
    l1 = mean + disc;   // larger
    float ux, uy;
    if (diff >= 0.f) { ux = diff + disc; uy = b; }
    else             { ux = b;           uy = disc - diff; }
    float nn = sqrtf(ux * ux + uy * uy);
    if (nn > 0.f) { ux /= nn; uy /= nn; } else { ux = 1.f; uy = 0.f; }
    V00 = -uy; V10 = ux;   // column 0 (l0)
    V01 =  ux; V11 = uy;   // column 1 (l1)
}

// ---------------------------------------------------------------- K1: setup-in-LDS + vor
// VERBATIM round 9 (validated; ~2-3 us). Block 0 inits the padded gml table.
__global__ __launch_bounds__(256, 2) void k_vorf(
        const float* __restrict__ mu, const float* __restrict__ sigma,
        float* __restrict__ val, int* __restrict__ vor,
        unsigned* __restrict__ gml) {
    __shared__ float4 lp[NJ];   // mmx, mmy, ia, ib2
    __shared__ float  lic[NJ];  // ic
    int tid = threadIdx.x;
    if (tid < NJ) {
        int j = tid;
        float a = sigma[j * 4 + 0];
        float b = sigma[j * 4 + 1];
        float c = sigma[j * 4 + 3];
        float l0, l1, V00, V10, V01, V11;
        eig2x2(a, b, c, l0, l1, V00, V10, V01, V11);
        float gmean = sqrtf(l0 * l1);
        float lsc0 = l0 / gmean * 4096.f;
        float lsc1 = l1 / gmean * 4096.f;
        float s00 = (V00 * V00 * lsc0 + V01 * V01 * lsc1) * 0.25f;
        float s01 = (V00 * V10 * lsc0 + V01 * V11 * lsc1) * 0.25f;
        float s11 = (V10 * V10 * lsc0 + V11 * V11 * lsc1) * 0.25f;
        float det = s00 * s11 - s01 * s01;
        float4 q;
        q.x = rintf(mu[j * 2 + 0] * 0.5f);   // jnp.round = ties-to-even = rintf
        q.y = rintf(mu[j * 2 + 1] * 0.5f);
        q.z =  s11 / det;                    // ia
        q.w = -2.f * s01 / det;              // ib2
        lp[j]  = q;
        lic[j] = s00 / det;                  // ic
    }
    if (blockIdx.x == 0 && tid < NJ) {       // init padded atomic table (stream-ordered)
        gml[tid * 16 + 0] = 0u;
        gml[tid * 16 + 1] = 0u;
        gml[tid * 16 + 2] = 0u;
    }
    __syncthreads();

    int t = blockIdx.x * 256 + tid;          // 0..131071
    int c = t & 511;
    int r = t >> 9;                          // 0..255
    const float SCALE = 512.0f / 511.0f;     // linspace(0, 512, 512) step
    float xc = (float)c * SCALE;
    float ya = (float)r * SCALE;
    float yb = (float)(r + 256) * SCALE;
    float bestA = 3.4e38f, bestB = 3.4e38f;
    int bjA = 0, bjB = 0;
    #pragma unroll 4
    for (int j = 0; j < NJ; ++j) {
        float4 p = lp[j];
        float ic = lic[j];
        float dx  = xc - p.x;
        float dyA = ya - p.y;
        float dyB = yb - p.y;
        float qA = p.z * dx * dx + p.w * dx * dyA + ic * dyA * dyA;
        float qB = p.z * dx * dx + p.w * dx * dyB + ic * dyB * dyB;
        if (qA < bestA) { bestA = qA; bjA = j; }   // first index on ties
        if (qB < bestB) { bestB = qB; bjB = j; }
    }
    int pA = r * WW + c, pB = (r + 256) * WW + c;
    val[pA] = expf(-0.5f * bestA); vor[pA] = bjA;
    val[pB] = expf(-0.5f * bestB); vor[pB] = bjB;
}

// ---------------------------------------------------------------- K2: tiled markers
// Round 9 structure (per-block LDS dedup -> ~2.5K padded global atomics) but
// 512 threads x 2 quad-passes instead of 256 x 4: doubles waves/SIMD (1 -> 2)
// to hide LDS latency, halves each thread's serial chain. Marker math, scan,
// and flush are bit-identical to the validated round 9.
__global__ __launch_bounds__(512) void k_markt(
        const float* __restrict__ mu, const float* __restrict__ sigma,
        const int* __restrict__ label, const float* __restrict__ pos_thres,
        const float* __restrict__ neg_thres,
        const float* __restrict__ val, const int* __restrict__ vor,
        unsigned* __restrict__ gml) {
    __shared__ float4   lvv[NJ];    // V00, V10, V01, V11
    __shared__ float2   lmu[NJ];    // mux, muy
    __shared__ float    lpt[NJ], lnt[NJ];
    __shared__ float    tval[THS][TLP];
    __shared__ int      tvor[THS][TLP];
    __shared__ unsigned lm0[NJ], lm1[NJ];
    __shared__ int      lflag[NJ];

    int tid = threadIdx.x;
    if (tid < NJ) {
        int j = tid;
        float a = sigma[j * 4 + 0];
        float b = sigma[j * 4 + 1];
        float cc = sigma[j * 4 + 3];
        float l0, l1, V00, V10, V01, V11;
        eig2x2(a, b, cc, l0, l1, V00, V10, V01, V11);
        lvv[j] = make_float4(V00, V10, V01, V11);
        lmu[j] = make_float2(mu[j * 2 + 0], mu[j * 2 + 1]);
        int cl = label[j];
        lpt[j] = pos_thres[cl];
        lnt[j] = neg_thres[cl];
        lm0[j] = 0u; lm1[j] = 0u; lflag[j] = 0;
    }

    int A0 = (blockIdx.x >> 4) * QT;   // 16x16 tiles of 32x32 quads
    int B0 = (blockIdx.x & 15) * QT;

    // ---- stage 34x34 halo tile (coalesced rows; OOB -> 0/0, never consumed)
    for (int idx = tid; idx < THS * THS; idx += 512) {
        int hu = idx / THS, hw = idx - hu * THS;
        int gy = A0 + hu - 1, gx = B0 + hw - 1;
        float vv = 0.f; int jv = 0;
        if (gy >= 0 && gy < HH && gx >= 0 && gx < WW) {
            int g = gy * WW + gx;
            vv = val[g]; jv = vor[g];
        }
        tval[hu][hw] = vv; tvor[hu][hw] = jv;
    }
    __syncthreads();

    int lane = tid & 63;
    #pragma unroll
    for (int p = 0; p < 2; ++p) {
        int u = tid >> 4;                    // 0..31
        int v = (tid & 15) + (p << 4);       // 0..15 / 16..31
        int a = A0 + u, b = B0 + v;
        bool aM = a > 0, aP = a < 511, bM = b > 0, bP = b < 511;
        int hmm_ = (aM && bM) ? tvor[u    ][v    ] : 0;
        int hm0_ =  aM        ? tvor[u    ][v + 1] : 0;
        int hm1_ = (aM && bP) ? tvor[u    ][v + 2] : 0;
        int h0m_ =  bM        ? tvor[u + 1][v    ] : 0;
        int h00_ =              tvor[u + 1][v + 1];
        int h0p_ =  bP        ? tvor[u + 1][v + 2] : 0;
        int hpm_ = (aP && bM) ? tvor[u + 2][v    ] : 0;
        int hp0_ =  aP        ? tvor[u + 2][v + 1] : 0;
        int hpp_ = (aP && bP) ? tvor[u + 2][v + 2] : 0;
        // exact-int Laplacian (3x3 ones, center -8, zero-padded) per full-res pixel
        int lap00 = -5 * h00_ + hmm_ + 2 * hm0_ + 2 * h0m_;
        int lap01 = -5 * h00_ + 2 * hm0_ + hm1_ + 2 * h0p_;
        int lap10 = -5 * h00_ + 2 * h0m_ + hpm_ + 2 * hp0_;
        int lap11 = -5 * h00_ + 2 * h0p_ + 2 * hp0_ + hpp_;
        int hv = h00_;
        float  pt = lpt[hv], nt = lnt[hv];
        float4 Vv = lvv[hv];
        float2 mv = lmu[hv];
        float m0 = -1.f, m1 = -1.f;   // r0,r1 >= 0, so -1 == "no valid pixel yet"

#define DO_PIXEL(U, V, LAP) {                                                  \
    int i = 2 * a + (U), jx = 2 * b + (V);                                     \
    float ry = ((float)i  * 511.0f) / 1023.0f;                                 \
    float rx = ((float)jx * 511.0f) / 1023.0f;                                 \
    int y0 = (int)ry; int y1 = min(y0 + 1, 511); float wy = ry - (float)y0;    \
    int x0 = (int)rx; int x1 = min(x0 + 1, 511); float wx = rx - (float)x0;    \
    int ly0 = y0 - A0 + 1, ly1 = y1 - A0 + 1;                                  \
    int lx0 = x0 - B0 + 1, lx1 = x1 - B0 + 1;                                  \
    float top = tval[ly0][lx0] * (1.f - wx) + tval[ly0][lx1] * wx;             \
    float bot = tval[ly1][lx0] * (1.f - wx) + tval[ly1][lx1] * wx;             \
    float vf  = top * (1.f - wy) + bot * wy;                                   \
    int mk = hv + 1;                                                           \
    if (vf < pt)     mk = 0;                                                   \
    if (vf < nt)     mk = NJ + 1;                                              \
    if ((LAP) != 0)  mk = NJ + 1;                                              \
    if (mk >= 1 && mk <= NJ) {                                                 \
        float dx = (float)jx - mv.x, dy = (float)i - mv.y;                     \
        float r0 = fabsf(Vv.x * dx + Vv.y * dy);                               \
        float r1 = fabsf(Vv.z * dx + Vv.w * dy);                               \
        m0 = fmaxf(m0, r0); m1 = fmaxf(m1, r1);                                \
    } }

        DO_PIXEL(0, 0, lap00)
        DO_PIXEL(0, 1, lap01)
        DO_PIXEL(1, 0, lap10)
        DO_PIXEL(1, 1, lap11)
#undef DO_PIXEL

        // wave segmented prefix-max over contiguous equal-inst runs (validated)
        int inst = (m0 >= 0.f) ? hv : -1;
        #pragma unroll
        for (int d = 1; d < 64; d <<= 1) {
            int   oi = __shfl_up(inst, d);
            float o0 = __shfl_up(m0, d);
            float o1 = __shfl_up(m1, d);
            if (lane >= d && oi == inst) { m0 = fmaxf(m0, o0); m1 = fmaxf(m1, o1); }
        }
        int ni = __shfl_down(inst, 1);
        bool leader = (inst >= 0) && (lane == 63 || ni != inst);
        if (leader) {   // few per wave -> cheap LDS atomics, on-CU
            atomicMax(&lm0[inst], __float_as_uint(m0));
            atomicMax(&lm1[inst], __float_as_uint(m1));
            lflag[inst] = 1;    // benign race, same value
        }
    }
    __syncthreads();

    // one global atomic triple per touched instance per block, padded lines
    if (tid < NJ && lflag[tid]) {
        atomicMax(&gml[tid * 16 + 0], lm0[tid]);
        atomicMax(&gml[tid * 16 + 1], lm1[tid]);
        gml[tid * 16 + 2] = 1u;   // benign race, same value; visible at dispatch end
    }
}

// ---------------------------------------------------------------- K3: loss + bottom-122 mean
// VERBATIM round 9 (validated).
__global__ __launch_bounds__(128) void k_loss(
        const float* __restrict__ sigma, const unsigned* __restrict__ gml,
        float* __restrict__ out) {
    __shared__ float lb[NJ];
    __shared__ float sv[NJ];
    __shared__ int   si[NJ];
    int j = threadIdx.x;

    float aa = sigma[j * 4 + 0];
    float bb = sigma[j * 4 + 1];
    float cc = sigma[j * 4 + 3];
    float ls0, ls1, V00, V10, V01, V11;
    eig2x2(aa, bb, cc, ls0, ls1, V00, V10, V01, V11);
    float g0 = __uint_as_float(gml[j * 16 + 0]);
    float g1 = __uint_as_float(gml[j * 16 + 1]);
    bool has = gml[j * 16 + 2] > 0u;
    float lt0 = has ? g0 * g0 : ls0;
    float lt1 = has ? g1 * g1 : ls1;
    float whr = (ls0 + ls1) + (lt0 + lt1);
    float tr  = ls0 * lt0 + ls1 * lt1;
    float det_sqrt = sqrtf(fmaxf((ls0 * ls1) * (lt0 * lt1), FEPS));
    whr = whr - 2.f * sqrtf(fmaxf(tr + 2.f * det_sqrt, FEPS));
    float dist = sqrtf(fmaxf(whr, FEPS));
    float scale = 2.f * fmaxf(sqrtf(fmaxf(sqrtf(fmaxf(det_sqrt, FEPS)), FEPS)), FEPS);
    dist = dist / scale;
    float li = 1.f - 1.f / (1.f + log1pf(dist));
    lb[j] = li;
    sv[j] = li;
    __syncthreads();

    // total sum (tree over LDS)
    #pragma unroll
    for (int s = 64; s > 0; s >>= 1) {
        if (j < s) sv[j] += sv[j + s];
        __syncthreads();
    }
    float total = sv[0];
    __syncthreads();

    // 6 largest (keep 122 smallest = ceil(128*0.95))
    float topsum = 0.f;
    #pragma unroll
    for (int it = 0; it < 6; ++it) {
        sv[j] = lb[j]; si[j] = j;
        __syncthreads();
        #pragma unroll
        for (int s = 64; s > 0; s >>= 1) {
            if (j < s) {
                if (sv[j + s] > sv[j]) { sv[j] = sv[j + s]; si[j] = si[j + s]; }
            }
            __syncthreads();
        }
        topsum += sv[0];
        if (j == 0) lb[si[0]] = -3.4e38f;
        __syncthreads();
    }

    if (j == 0) out[0] = 1.0f * (total - topsum) / 122.f;   // LOSS_WEIGHT = 1
}

// ---------------------------------------------------------------- launch
extern "C" void kernel_launch(void* const* d_in, const int* in_sizes, int n_in,
                              void* d_out, int out_size, void* d_ws, size_t ws_size,
                              hipStream_t stream) {
    const float* mu        = (const float*)d_in[0];
    const float* sigma     = (const float*)d_in[1];
    const int*   label     = (const int*)d_in[2];
    // d_in[3] = image: unused by the reference's forward pass
    const float* pos_thres = (const float*)d_in[4];
    const float* neg_thres = (const float*)d_in[5];
    float* out = (float*)d_out;

    // workspace layout
    float*    val = (float*)d_ws;                                   // 512*512 f32 (1 MiB)
    int*      vor = (int*)((char*)d_ws + (size_t)HH * WW * 4);      // 512*512 i32 (1 MiB)
    unsigned* gml = (unsigned*)((char*)d_ws + 2ull * HH * WW * 4);  // 128 * 16 u32 (8 KiB, 64B/inst)

    k_vorf <<<(HH * WW / 2) / 256, 256, 0, stream>>>(mu, sigma, val, vor, gml);
    k_markt<<<256, 512, 0, stream>>>(mu, sigma, label, pos_thres, neg_thres,
                                     val, vor, gml);
    k_loss <<<1, 128, 0, stream>>>(sigma, gml, out);
}

// Round 11
// 27.585 us; speedup vs baseline: 2.3505x; 1.0750x over previous
//
#include <hip/hip_runtime.h>
#include <math.h>

#define NJ 128
#define HH 512
#define WW 512
#define FEPS 1e-7f
#define QT  32          // quad tile edge (quads per block side)
#define THS (QT + 2)    // 34: tile + 1-cell halo
#define TLP 36          // padded LDS row pitch

// ---------------------------------------------------------------- eig helper
// 2x2 symmetric eigendecomposition, ascending order (matches jnp.linalg.eigh).
// Bit-identical to validated rounds 2-10.
__device__ __forceinline__ void eig2x2(float a, float b, float c,
                                       float& l0, float& l1,
                                       float& V00, float& V10, float& V01, float& V11) {
    float mean = 0.5f * (a + c);
    float diff = 0.5f * (a - c);
    float disc = sqrtf(diff * diff + b * b);
    l0 = mean - disc;   // smaller
    l1 = mean + disc;   // larger
    float ux, uy;
    if (diff >= 0.f) { ux = diff + disc; uy = b; }
    else             { ux = b;           uy = disc - diff; }
    float nn = sqrtf(ux * ux + uy * uy);
    if (nn > 0.f) { ux /= nn; uy /= nn; } else { ux = 1.f; uy = 0.f; }
    V00 = -uy; V10 = ux;   // column 0 (l0)
    V01 =  ux; V11 = uy;   // column 1 (l1)
}

// ---------------------------------------------------------------- K1: setup-in-LDS + vor
// VERBATIM round 9/10 (validated; ~3 us). Block 0 inits the padded gml table.
__global__ __launch_bounds__(256, 2) void k_vorf(
        const float* __restrict__ mu, const float* __restrict__ sigma,
        float* __restrict__ val, int* __restrict__ vor,
        unsigned* __restrict__ gml) {
    __shared__ float4 lp[NJ];   // mmx, mmy, ia, ib2
    __shared__ float  lic[NJ];  // ic
    int tid = threadIdx.x;
    if (tid < NJ) {
        int j = tid;
        float a = sigma[j * 4 + 0];
        float b = sigma[j * 4 + 1];
        float c = sigma[j * 4 + 3];
        float l0, l1, V00, V10, V01, V11;
        eig2x2(a, b, c, l0, l1, V00, V10, V01, V11);
        float gmean = sqrtf(l0 * l1);
        float lsc0 = l0 / gmean * 4096.f;
        float lsc1 = l1 / gmean * 4096.f;
        float s00 = (V00 * V00 * lsc0 + V01 * V01 * lsc1) * 0.25f;
        float s01 = (V00 * V10 * lsc0 + V01 * V11 * lsc1) * 0.25f;
        float s11 = (V10 * V10 * lsc0 + V11 * V11 * lsc1) * 0.25f;
        float det = s00 * s11 - s01 * s01;
        float4 q;
        q.x = rintf(mu[j * 2 + 0] * 0.5f);   // jnp.round = ties-to-even = rintf
        q.y = rintf(mu[j * 2 + 1] * 0.5f);
        q.z =  s11 / det;                    // ia
        q.w = -2.f * s01 / det;              // ib2
        lp[j]  = q;
        lic[j] = s00 / det;                  // ic
    }
    if (blockIdx.x == 0 && tid < NJ) {       // init padded atomic table (stream-ordered)
        gml[tid * 16 + 0] = 0u;
        gml[tid * 16 + 1] = 0u;
        gml[tid * 16 + 2] = 0u;
    }
    __syncthreads();

    int t = blockIdx.x * 256 + tid;          // 0..131071
    int c = t & 511;
    int r = t >> 9;                          // 0..255
    const float SCALE = 512.0f / 511.0f;     // linspace(0, 512, 512) step
    float xc = (float)c * SCALE;
    float ya = (float)r * SCALE;
    float yb = (float)(r + 256) * SCALE;
    float bestA = 3.4e38f, bestB = 3.4e38f;
    int bjA = 0, bjB = 0;
    #pragma unroll 4
    for (int j = 0; j < NJ; ++j) {
        float4 p = lp[j];
        float ic = lic[j];
        float dx  = xc - p.x;
        float dyA = ya - p.y;
        float dyB = yb - p.y;
        float qA = p.z * dx * dx + p.w * dx * dyA + ic * dyA * dyA;
        float qB = p.z * dx * dx + p.w * dx * dyB + ic * dyB * dyB;
        if (qA < bestA) { bestA = qA; bjA = j; }   // first index on ties
        if (qB < bestB) { bestB = qB; bjB = j; }
    }
    int pA = r * WW + c, pB = (r + 256) * WW + c;
    val[pA] = expf(-0.5f * bestA); vor[pA] = bjA;
    val[pB] = expf(-0.5f * bestB); vor[pB] = bjB;
}

// ---------------------------------------------------------------- K2: tiled markers
// Round 9/10 structure (per-block LDS dedup -> ~2.5K padded global atomics),
// now 1024 threads x 1 quad/thread: 4 waves/SIMD to hide staging/LDS latency,
// single marker pass + single segmented scan per thread. Marker math, scan,
// and flush bit-identical to validated rounds 9-10.
__global__ __launch_bounds__(1024) void k_markt(
        const float* __restrict__ mu, const float* __restrict__ sigma,
        const int* __restrict__ label, const float* __restrict__ pos_thres,
        const float* __restrict__ neg_thres,
        const float* __restrict__ val, const int* __restrict__ vor,
        unsigned* __restrict__ gml) {
    __shared__ float4   lvv[NJ];    // V00, V10, V01, V11
    __shared__ float2   lmu[NJ];    // mux, muy
    __shared__ float    lpt[NJ], lnt[NJ];
    __shared__ float    tval[THS][TLP];
    __shared__ int      tvor[THS][TLP];
    __shared__ unsigned lm0[NJ], lm1[NJ];
    __shared__ int      lflag[NJ];

    int tid = threadIdx.x;
    if (tid < NJ) {
        int j = tid;
        float a = sigma[j * 4 + 0];
        float b = sigma[j * 4 + 1];
        float cc = sigma[j * 4 + 3];
        float l0, l1, V00, V10, V01, V11;
        eig2x2(a, b, cc, l0, l1, V00, V10, V01, V11);
        lvv[j] = make_float4(V00, V10, V01, V11);
        lmu[j] = make_float2(mu[j * 2 + 0], mu[j * 2 + 1]);
        int cl = label[j];
        lpt[j] = pos_thres[cl];
        lnt[j] = neg_thres[cl];
        lm0[j] = 0u; lm1[j] = 0u; lflag[j] = 0;
    }

    int A0 = (blockIdx.x >> 4) * QT;   // 16x16 tiles of 32x32 quads
    int B0 = (blockIdx.x & 15) * QT;

    // ---- stage 34x34 halo tile (coalesced rows; OOB -> 0/0, never consumed)
    for (int idx = tid; idx < THS * THS; idx += 1024) {
        int hu = idx / THS, hw = idx - hu * THS;
        int gy = A0 + hu - 1, gx = B0 + hw - 1;
        float vv = 0.f; int jv = 0;
        if (gy >= 0 && gy < HH && gx >= 0 && gx < WW) {
            int g = gy * WW + gx;
            vv = val[g]; jv = vor[g];
        }
        tval[hu][hw] = vv; tvor[hu][hw] = jv;
    }
    __syncthreads();

    int lane = tid & 63;
    {
        int u = tid >> 5;                    // 0..31
        int v = tid & 31;                    // 0..31
        int a = A0 + u, b = B0 + v;
        bool aM = a > 0, aP = a < 511, bM = b > 0, bP = b < 511;
        int hmm_ = (aM && bM) ? tvor[u    ][v    ] : 0;
        int hm0_ =  aM        ? tvor[u    ][v + 1] : 0;
        int hm1_ = (aM && bP) ? tvor[u    ][v + 2] : 0;
        int h0m_ =  bM        ? tvor[u + 1][v    ] : 0;
        int h00_ =              tvor[u + 1][v + 1];
        int h0p_ =  bP        ? tvor[u + 1][v + 2] : 0;
        int hpm_ = (aP && bM) ? tvor[u + 2][v    ] : 0;
        int hp0_ =  aP        ? tvor[u + 2][v + 1] : 0;
        int hpp_ = (aP && bP) ? tvor[u + 2][v + 2] : 0;
        // exact-int Laplacian (3x3 ones, center -8, zero-padded) per full-res pixel
        int lap00 = -5 * h00_ + hmm_ + 2 * hm0_ + 2 * h0m_;
        int lap01 = -5 * h00_ + 2 * hm0_ + hm1_ + 2 * h0p_;
        int lap10 = -5 * h00_ + 2 * h0m_ + hpm_ + 2 * hp0_;
        int lap11 = -5 * h00_ + 2 * h0p_ + 2 * hp0_ + hpp_;
        int hv = h00_;
        float  pt = lpt[hv], nt = lnt[hv];
        float4 Vv = lvv[hv];
        float2 mv = lmu[hv];
        float m0 = -1.f, m1 = -1.f;   // r0,r1 >= 0, so -1 == "no valid pixel yet"

#define DO_PIXEL(U, V, LAP) {                                                  \
    int i = 2 * a + (U), jx = 2 * b + (V);                                     \
    float ry = ((float)i  * 511.0f) / 1023.0f;                                 \
    float rx = ((float)jx * 511.0f) / 1023.0f;                                 \
    int y0 = (int)ry; int y1 = min(y0 + 1, 511); float wy = ry - (float)y0;    \
    int x0 = (int)rx; int x1 = min(x0 + 1, 511); float wx = rx - (float)x0;    \
    int ly0 = y0 - A0 + 1, ly1 = y1 - A0 + 1;                                  \
    int lx0 = x0 - B0 + 1, lx1 = x1 - B0 + 1;                                  \
    float top = tval[ly0][lx0] * (1.f - wx) + tval[ly0][lx1] * wx;             \
    float bot = tval[ly1][lx0] * (1.f - wx) + tval[ly1][lx1] * wx;             \
    float vf  = top * (1.f - wy) + bot * wy;                                   \
    int mk = hv + 1;                                                           \
    if (vf < pt)     mk = 0;                                                   \
    if (vf < nt)     mk = NJ + 1;                                              \
    if ((LAP) != 0)  mk = NJ + 1;                                              \
    if (mk >= 1 && mk <= NJ) {                                                 \
        float dx = (float)jx - mv.x, dy = (float)i - mv.y;                     \
        float r0 = fabsf(Vv.x * dx + Vv.y * dy);                               \
        float r1 = fabsf(Vv.z * dx + Vv.w * dy);                               \
        m0 = fmaxf(m0, r0); m1 = fmaxf(m1, r1);                                \
    } }

        DO_PIXEL(0, 0, lap00)
        DO_PIXEL(0, 1, lap01)
        DO_PIXEL(1, 0, lap10)
        DO_PIXEL(1, 1, lap11)
#undef DO_PIXEL

        // wave segmented prefix-max over contiguous equal-inst runs (validated)
        int inst = (m0 >= 0.f) ? hv : -1;
        #pragma unroll
        for (int d = 1; d < 64; d <<= 1) {
            int   oi = __shfl_up(inst, d);
            float o0 = __shfl_up(m0, d);
            float o1 = __shfl_up(m1, d);
            if (lane >= d && oi == inst) { m0 = fmaxf(m0, o0); m1 = fmaxf(m1, o1); }
        }
        int ni = __shfl_down(inst, 1);
        bool leader = (inst >= 0) && (lane == 63 || ni != inst);
        if (leader) {   // few per wave -> cheap LDS atomics, on-CU
            atomicMax(&lm0[inst], __float_as_uint(m0));
            atomicMax(&lm1[inst], __float_as_uint(m1));
            lflag[inst] = 1;    // benign race, same value
        }
    }
    __syncthreads();

    // one global atomic triple per touched instance per block, padded lines
    if (tid < NJ && lflag[tid]) {
        atomicMax(&gml[tid * 16 + 0], lm0[tid]);
        atomicMax(&gml[tid * 16 + 1], lm1[tid]);
        gml[tid * 16 + 2] = 1u;   // benign race, same value; visible at dispatch end
    }
}

// ---------------------------------------------------------------- K3: loss + bottom-122 mean
// Rank-select version: no 6-round argmax tree (42 barriers) -- each thread
// computes its rank by comparison count (128 broadcast LDS reads, 0 barriers),
// top-6 = rank < 6 with index tie-break (matches top_k first-index-on-ties).
__global__ __launch_bounds__(128) void k_loss(
        const float* __restrict__ sigma, const unsigned* __restrict__ gml,
        float* __restrict__ out) {
    __shared__ float lb[NJ];
    __shared__ float wtot[2], wtop[2];
    int j = threadIdx.x;

    float aa = sigma[j * 4 + 0];
    float bb = sigma[j * 4 + 1];
    float cc = sigma[j * 4 + 3];
    float ls0, ls1, V00, V10, V01, V11;
    eig2x2(aa, bb, cc, ls0, ls1, V00, V10, V01, V11);
    float g0 = __uint_as_float(gml[j * 16 + 0]);
    float g1 = __uint_as_float(gml[j * 16 + 1]);
    bool has = gml[j * 16 + 2] > 0u;
    float lt0 = has ? g0 * g0 : ls0;
    float lt1 = has ? g1 * g1 : ls1;
    float whr = (ls0 + ls1) + (lt0 + lt1);
    float tr  = ls0 * lt0 + ls1 * lt1;
    float det_sqrt = sqrtf(fmaxf((ls0 * ls1) * (lt0 * lt1), FEPS));
    whr = whr - 2.f * sqrtf(fmaxf(tr + 2.f * det_sqrt, FEPS));
    float dist = sqrtf(fmaxf(whr, FEPS));
    float scale = 2.f * fmaxf(sqrtf(fmaxf(sqrtf(fmaxf(det_sqrt, FEPS)), FEPS)), FEPS);
    dist = dist / scale;
    float li = 1.f - 1.f / (1.f + log1pf(dist));
    lb[j] = li;
    __syncthreads();

    // rank of li among all 128 (value desc, index asc tie-break)
    int rank = 0;
    #pragma unroll 8
    for (int t = 0; t < NJ; ++t) {
        float o = lb[t];                       // broadcast read, conflict-free
        rank += (o > li || (o == li && t < j)) ? 1 : 0;
    }
    float tot = li;
    float top = (rank < 6) ? li : 0.f;        // 6 largest (keep 122 = ceil(128*.95))

    // wave reduce (64 lanes), then combine the 2 waves via LDS
    #pragma unroll
    for (int d = 32; d > 0; d >>= 1) {
        tot += __shfl_down(tot, d);
        top += __shfl_down(top, d);
    }
    if ((j & 63) == 0) { wtot[j >> 6] = tot; wtop[j >> 6] = top; }
    __syncthreads();
    if (j == 0)
        out[0] = 1.0f * ((wtot[0] + wtot[1]) - (wtop[0] + wtop[1])) / 122.f;  // LOSS_WEIGHT = 1
}

// ---------------------------------------------------------------- launch
extern "C" void kernel_launch(void* const* d_in, const int* in_sizes, int n_in,
                              void* d_out, int out_size, void* d_ws, size_t ws_size,
                              hipStream_t stream) {
    const float* mu        = (const float*)d_in[0];
    const float* sigma     = (const float*)d_in[1];
    const int*   label     = (const int*)d_in[2];
    // d_in[3] = image: unused by the reference's forward pass
    const float* pos_thres = (const float*)d_in[4];
    const float* neg_thres = (const float*)d_in[5];
    float* out = (float*)d_out;

    // workspace layout
    float*    val = (float*)d_ws;                                   // 512*512 f32 (1 MiB)
    int*      vor = (int*)((char*)d_ws + (size_t)HH * WW * 4);      // 512*512 i32 (1 MiB)
    unsigned* gml = (unsigned*)((char*)d_ws + 2ull * HH * WW * 4);  // 128 * 16 u32 (8 KiB, 64B/inst)

    k_vorf <<<(HH * WW / 2) / 256, 256, 0, stream>>>(mu, sigma, val, vor, gml);
    k_markt<<<256, 1024, 0, stream>>>(mu, sigma, label, pos_thres, neg_thres,
                                      val, vor, gml);
    k_loss <<<1, 128, 0, stream>>>(sigma, gml, out);
}